// Round 1
// baseline (207.401 us; speedup 1.0000x reference)
//
#include <hip/hip_runtime.h>

#define N_TOK  8192
#define KDIM   4096
#define NE     16
#define NSLICE 4                   // K split across blocks
#define TB     64                  // tokens per block (= wave width)
#define BK     32                  // k per staged chunk per wave
#define NWAVE  4                   // waves per block (256 threads)
#define KSLICE (KDIM / NSLICE)     // 1024
#define KWAVE  (KSLICE / NWAVE)    // 256
#define NCHUNK (KWAVE / BK)        // 8
#define LSTR   (BK + 1)            // 33: odd stride -> <=2-way LDS conflicts (free)

// Kernel A: partial logits. Lane <-> token, k wave-uniform so gate reads are
// scalar (s_load) and the inner loop is v_fmac(v_acc, s_gate, v_x).
// Per-wave private LDS tile -> NO __syncthreads in the K loop.
__global__ __launch_bounds__(256, 2)
void router_partial(const float* __restrict__ x, const float* __restrict__ gate,
                    float* __restrict__ ws) {
  __shared__ float lds[NWAVE * TB * LSTR];   // 4*64*33*4B = 33.8 KB -> 2+ blocks/CU
  const int tid  = threadIdx.x;
  const int lane = tid & 63;
  const int w    = __builtin_amdgcn_readfirstlane(tid >> 6);  // force SGPR: keeps gate addr uniform
  const int g    = blockIdx.x >> 2;          // token group
  const int s    = blockIdx.x & 3;           // k-slice
  const int t0   = g * TB;
  const int k0   = s * KSLICE + w * KWAVE;
  float* xt = lds + w * (TB * LSTR);

  float acc[NE];
#pragma unroll
  for (int e = 0; e < NE; ++e) acc[e] = 0.f;

  // stage chunk 0: 64 tok x 32 k = 512 float4, 8 per lane, coalesced along k
  float4 buf[8];
#pragma unroll
  for (int i = 0; i < 8; ++i) {
    int f = i * 64 + lane;
    int t = f >> 3, c4 = f & 7;              // 8 float4 per token row
    buf[i] = *(const float4*)(x + (size_t)(t0 + t) * KDIM + (k0 + c4 * 4));
  }

  for (int c = 0; c < NCHUNK; ++c) {
    // write staged chunk to LDS (bank-spread via odd stride)
#pragma unroll
    for (int i = 0; i < 8; ++i) {
      int f = i * 64 + lane;
      int t = f >> 3, c4 = f & 7;
      float* p = xt + t * LSTR + c4 * 4;
      p[0] = buf[i].x; p[1] = buf[i].y; p[2] = buf[i].z; p[3] = buf[i].w;
    }
    // prefetch next chunk before compute: global latency hidden by 512 FMAs
    if (c + 1 < NCHUNK) {
      int kc = k0 + (c + 1) * BK;
#pragma unroll
      for (int i = 0; i < 8; ++i) {
        int f = i * 64 + lane;
        int t = f >> 3, c4 = f & 7;
        buf[i] = *(const float4*)(x + (size_t)(t0 + t) * KDIM + (kc + c4 * 4));
      }
    }
    int kc = k0 + c * BK;
    const float* xrow = xt + lane * LSTR;    // bank = (lane + k) % 32 -> 2-way, free
#pragma unroll 8
    for (int k = 0; k < BK; ++k) {
      float xv = xrow[k];
      const float* grow = gate + (size_t)(kc + k) * NE;  // wave-uniform -> s_load_dwordx16
#pragma unroll
      for (int e = 0; e < NE; ++e) acc[e] = fmaf(xv, grow[e], acc[e]);
    }
  }

  // cross-wave reduction of the 4 k-subslices, then one ws write per block
  __syncthreads();                           // waves done reading xt before overwrite
  float* red = lds;
#pragma unroll
  for (int e = 0; e < NE; ++e) red[(w * 64 + lane) * 17 + e] = acc[e];
  __syncthreads();
  {
    int p0 = tid * 4;                        // 1024 (token,e) pairs, 4 per thread
    int t  = p0 >> 4, e0 = p0 & 15;
    float v[4];
#pragma unroll
    for (int j = 0; j < 4; ++j) {
      float sum = 0.f;
#pragma unroll
      for (int ww = 0; ww < NWAVE; ++ww) sum += red[(ww * 64 + t) * 17 + e0 + j];
      v[j] = sum;
    }
    *(float4*)(ws + ((size_t)s * N_TOK + (t0 + t)) * NE + e0) =
        make_float4(v[0], v[1], v[2], v[3]);
  }
}

// Kernel B: sum 4 slice partials, top-2 (earliest-index tie-break = jax top_k),
// sigmoid, scatter into (E,N) scores; token_indices[e][t] = t (as float).
__global__ __launch_bounds__(64)
void router_finalize(const float* __restrict__ ws, float* __restrict__ out) {
  int t = blockIdx.x * 64 + threadIdx.x;
  float l[NE];
#pragma unroll
  for (int e = 0; e < NE; ++e) l[e] = 0.f;
#pragma unroll
  for (int s = 0; s < NSLICE; ++s) {
    const float* row = ws + ((size_t)s * N_TOK + t) * NE;  // 64B contiguous/thread
#pragma unroll
    for (int e = 0; e < NE; ++e) l[e] += row[e];
  }
  int i1 = 0; float v1 = l[0];
#pragma unroll
  for (int e = 1; e < NE; ++e) { if (l[e] > v1) { v1 = l[e]; i1 = e; } }
  int i2 = -1; float v2 = -1e30f;
#pragma unroll
  for (int e = 0; e < NE; ++e) { if (e != i1 && l[e] > v2) { v2 = l[e]; i2 = e; } }
  float s1 = 1.f / (1.f + __expf(-v1));
  float s2 = 1.f / (1.f + __expf(-v2));
  float* scores = out;
  float* tix    = out + (size_t)NE * N_TOK;
  float tf = (float)t;
#pragma unroll
  for (int e = 0; e < NE; ++e) {             // coalesced across lanes per e
    scores[(size_t)e * N_TOK + t] = (e == i1) ? s1 : ((e == i2) ? s2 : 0.f);
    tix[(size_t)e * N_TOK + t]    = tf;
  }
}

extern "C" void kernel_launch(void* const* d_in, const int* in_sizes, int n_in,
                              void* d_out, int out_size, void* d_ws, size_t ws_size,
                              hipStream_t stream) {
  const float* x    = (const float*)d_in[0];
  const float* gate = (const float*)d_in[1];
  float* out = (float*)d_out;
  float* ws  = (float*)d_ws;   // needs NSLICE*N_TOK*NE*4 = 2 MB
  router_partial<<<dim3(N_TOK / TB * NSLICE), dim3(256), 0, stream>>>(x, gate, ws);
  router_finalize<<<dim3(N_TOK / 64), dim3(64), 0, stream>>>(ws, out);
}